// Round 4
// baseline (788.048 us; speedup 1.0000x reference)
//
#include <hip/hip_runtime.h>
#include <hip/hip_bf16.h>
#include <math.h>

#define BN_EPS 1e-5f

typedef __attribute__((ext_vector_type(8))) short short8;
typedef __attribute__((ext_vector_type(4))) float floatx4;

// ---------------- zero: cnt[N]=0, stats[1024]=0 ----------------
__global__ void zero_kernel(int* __restrict__ cnt, float* __restrict__ stats, int N) {
    int i = blockIdx.x * blockDim.x + threadIdx.x;
    if (i < N) cnt[i] = 0;
    if (i < 1024) stats[i] = 0.0f;
}

// ---------------- histogram over dst ----------------
__global__ void hist_kernel(const int* __restrict__ dst, int* __restrict__ cnt, int E) {
    int e = blockIdx.x * blockDim.x + threadIdx.x;
    if (e < E)
        __hip_atomic_fetch_add(&cnt[dst[e]], 1, __ATOMIC_RELAXED, __HIP_MEMORY_SCOPE_AGENT);
}

// dinv = rsqrt(deg+1)  (self loop)
__global__ void dinv_kernel(const int* __restrict__ cnt, float* __restrict__ dinv, int N) {
    int i = blockIdx.x * blockDim.x + threadIdx.x;
    if (i < N) dinv[i] = rsqrtf((float)cnt[i] + 1.0f);
}

// ---------------- exclusive scan (3 kernels), 1024 elems/block ----------------
__global__ __launch_bounds__(256) void scan_part(const int* __restrict__ cnt,
                                                 int* __restrict__ out,
                                                 int* __restrict__ blk, int N) {
    __shared__ int lds[256];
    int t = threadIdx.x;
    int base = blockIdx.x * 1024 + t * 4;
    int v[4];
    int s = 0;
#pragma unroll
    for (int i = 0; i < 4; ++i) { v[i] = (base + i < N) ? cnt[base + i] : 0; s += v[i]; }
    lds[t] = s;
    __syncthreads();
    for (int off = 1; off < 256; off <<= 1) {
        int x = (t >= off) ? lds[t - off] : 0;
        __syncthreads();
        lds[t] += x;
        __syncthreads();
    }
    int excl = lds[t] - s;
    if (t == 255) blk[blockIdx.x] = lds[255];
    int run = excl;
#pragma unroll
    for (int i = 0; i < 4; ++i) {
        if (base + i < N) out[base + i] = run;
        run += v[i];
    }
}

__global__ void scan_blk(int* __restrict__ blk, int nb) {
    if (threadIdx.x == 0) {
        int run = 0;
        for (int i = 0; i < nb; ++i) { int v = blk[i]; blk[i] = run; run += v; }
    }
}

__global__ void scan_add(int* __restrict__ rowptr, const int* __restrict__ blk,
                         int* __restrict__ cursor, int N) {
    int i = blockIdx.x * blockDim.x + threadIdx.x;
    if (i < N) {
        int v = rowptr[i] + blk[i >> 10];
        rowptr[i] = v;
        cursor[i] = v;
    }
}

// ---------------- partitioned fill: CSR bucket scatter with XCD write locality ----
// block b: scans edge chunk b/8, keeps edges with dst in contiguous partition b&7.
// Partition assignment is a pure function of dst -> correctness independent of
// block->XCD mapping; locality is the heuristic (blockIdx%8 ~ XCD round-robin).
__global__ __launch_bounds__(256) void fill_part_kernel(
    const int* __restrict__ src, const int* __restrict__ dst,
    int* __restrict__ cursor, int* __restrict__ ssrc, int E, float pinv)
{
    int part   = blockIdx.x & 7;
    int chunk  = blockIdx.x >> 3;
    int nchunk = gridDim.x >> 3;
    int per = (E + nchunk - 1) / nchunk;
    int e0 = chunk * per;
    int e1 = min(e0 + per, E);
    for (int e = e0 + threadIdx.x; e < e1; e += 256) {
        int d = dst[e];
        int p = (int)((float)d * pinv);
        p = p > 7 ? 7 : p;
        if (p == part) {
            int pos = __hip_atomic_fetch_add(&cursor[d], 1, __ATOMIC_RELAXED, __HIP_MEMORY_SCOPE_AGENT);
            ssrc[pos] = src[e];
        }
    }
}

// ---------------- Wc = proj_W @ W1  (256x256 @ 256x128) ----------------
__global__ void wc_kernel(const float* __restrict__ PW, const float* __restrict__ W1,
                          float* __restrict__ Wc) {
    int r = blockIdx.x;
    int c = threadIdx.x;
    float acc = 0.f;
    for (int k = 0; k < 256; ++k) acc = fmaf(PW[r * 256 + k], W1[k * 128 + c], acc);
    Wc[r * 128 + c] = acc;
}

__global__ void bc_kernel(const float* __restrict__ pb, const float* __restrict__ W1,
                          float* __restrict__ bc) {
    int c = threadIdx.x;
    float acc = 0.f;
    for (int k = 0; k < 256; ++k) acc = fmaf(pb[k], W1[k * 128 + c], acc);
    bc[c] = acc;
}

// ---------------- pack W [K x 128] fp32 -> fragment-order bf16 ----------------
template <int K>
__global__ void packW_kernel(const float* __restrict__ W, __hip_bfloat16* __restrict__ Wf) {
    int t = blockIdx.x * 256 + threadIdx.x;
    if (t >= (K / 32) * 8 * 64 * 8) return;
    int j    = t & 7;
    int lane = (t >> 3) & 63;
    int ct   = (t >> 9) & 7;
    int kc   = t >> 12;
    int k = kc * 32 + ((lane >> 4) & 3) * 8 + j;
    int c = ct * 16 + (lane & 15);
    Wf[t] = __float2bfloat16(W[k * 128 + c]);
}

__device__ inline short8 cvt8(float4 a, float4 b) {
    __hip_bfloat162 p0 = __float22bfloat162_rn(make_float2(a.x, a.y));
    __hip_bfloat162 p1 = __float22bfloat162_rn(make_float2(a.z, a.w));
    __hip_bfloat162 p2 = __float22bfloat162_rn(make_float2(b.x, b.y));
    __hip_bfloat162 p3 = __float22bfloat162_rn(make_float2(b.z, b.w));
    union { short8 s; __hip_bfloat162 h[4]; } u;
    u.h[0] = p0; u.h[1] = p1; u.h[2] = p2; u.h[3] = p3;
    return u.s;
}

// ---------------- MFMA GEMM: Hs(bf16) = (op(X[N,K]) @ W[K,128] + bias) * dinv[row] ----------------
template <int K, bool BN>
__global__ __launch_bounds__(256) void mfma_gemm(
    const float* __restrict__ X, const short* __restrict__ Wf,
    const float* __restrict__ bias, const float* __restrict__ dinv,
    const float* __restrict__ scale, const float* __restrict__ shift,
    __hip_bfloat16* __restrict__ Hs, int N)
{
    const int wave = threadIdx.x >> 6;
    const int lane = threadIdx.x & 63;
    const int l16  = lane & 15;
    const int q    = lane >> 4;            // 0..3
    const int r0   = blockIdx.x * 128 + wave * 32;

    const int ra0 = min(r0 + l16, N - 1);
    const int ra1 = min(r0 + 16 + l16, N - 1);
    const float* pA0 = X + (size_t)ra0 * K + q * 8;
    const float* pA1 = X + (size_t)ra1 * K + q * 8;
    const short8* WF = (const short8*)Wf;

    floatx4 acc[2][8];
#pragma unroll
    for (int rt = 0; rt < 2; ++rt)
#pragma unroll
        for (int ct = 0; ct < 8; ++ct) { acc[rt][ct][0] = 0.f; acc[rt][ct][1] = 0.f; acc[rt][ct][2] = 0.f; acc[rt][ct][3] = 0.f; }

#pragma unroll
    for (int kc = 0; kc < K / 32; ++kc) {
        short8 b[8];
#pragma unroll
        for (int ct = 0; ct < 8; ++ct) b[ct] = WF[(kc * 8 + ct) * 64 + lane];

        float4 x00 = *(const float4*)(pA0 + kc * 32);
        float4 x01 = *(const float4*)(pA0 + kc * 32 + 4);
        float4 x10 = *(const float4*)(pA1 + kc * 32);
        float4 x11 = *(const float4*)(pA1 + kc * 32 + 4);
        if (BN) {
            float4 sc0 = *(const float4*)(scale + kc * 32 + q * 8);
            float4 sc1 = *(const float4*)(scale + kc * 32 + q * 8 + 4);
            float4 sh0 = *(const float4*)(shift + kc * 32 + q * 8);
            float4 sh1 = *(const float4*)(shift + kc * 32 + q * 8 + 4);
            x00.x = fmaxf(fmaf(x00.x, sc0.x, sh0.x), 0.f);
            x00.y = fmaxf(fmaf(x00.y, sc0.y, sh0.y), 0.f);
            x00.z = fmaxf(fmaf(x00.z, sc0.z, sh0.z), 0.f);
            x00.w = fmaxf(fmaf(x00.w, sc0.w, sh0.w), 0.f);
            x01.x = fmaxf(fmaf(x01.x, sc1.x, sh1.x), 0.f);
            x01.y = fmaxf(fmaf(x01.y, sc1.y, sh1.y), 0.f);
            x01.z = fmaxf(fmaf(x01.z, sc1.z, sh1.z), 0.f);
            x01.w = fmaxf(fmaf(x01.w, sc1.w, sh1.w), 0.f);
            x10.x = fmaxf(fmaf(x10.x, sc0.x, sh0.x), 0.f);
            x10.y = fmaxf(fmaf(x10.y, sc0.y, sh0.y), 0.f);
            x10.z = fmaxf(fmaf(x10.z, sc0.z, sh0.z), 0.f);
            x10.w = fmaxf(fmaf(x10.w, sc0.w, sh0.w), 0.f);
            x11.x = fmaxf(fmaf(x11.x, sc1.x, sh1.x), 0.f);
            x11.y = fmaxf(fmaf(x11.y, sc1.y, sh1.y), 0.f);
            x11.z = fmaxf(fmaf(x11.z, sc1.z, sh1.z), 0.f);
            x11.w = fmaxf(fmaf(x11.w, sc1.w, sh1.w), 0.f);
        }
        short8 a0 = cvt8(x00, x01);
        short8 a1 = cvt8(x10, x11);
#pragma unroll
        for (int ct = 0; ct < 8; ++ct) {
            acc[0][ct] = __builtin_amdgcn_mfma_f32_16x16x32_bf16(a0, b[ct], acc[0][ct], 0, 0, 0);
            acc[1][ct] = __builtin_amdgcn_mfma_f32_16x16x32_bf16(a1, b[ct], acc[1][ct], 0, 0, 0);
        }
    }

    float bb[8];
#pragma unroll
    for (int ct = 0; ct < 8; ++ct) bb[ct] = bias ? bias[ct * 16 + l16] : 0.f;

#pragma unroll
    for (int rt = 0; rt < 2; ++rt) {
        int rbase = r0 + rt * 16 + q * 4;
        float dv[4];
#pragma unroll
        for (int i = 0; i < 4; ++i) dv[i] = dinv[min(rbase + i, N - 1)];
#pragma unroll
        for (int ct = 0; ct < 8; ++ct) {
#pragma unroll
            for (int i = 0; i < 4; ++i) {
                int row = rbase + i;
                if (row < N)
                    Hs[(size_t)row * 128 + ct * 16 + l16] =
                        __float2bfloat16((acc[rt][ct][i] + bb[ct]) * dv[i]);
            }
        }
    }
}

// ---------------- gather-reduce aggregation over bf16 Hs ----------------
// Half-wave pairs: lanes 0-31 process even-indexed edges, lanes 32-63 odd.
// Each lane loads uint2 (4 bf16 channels); unroll x4 -> 8 rows in flight/wave.
__device__ inline void acc2(uint2 u, float& x0, float& x1, float& x2, float& x3) {
    x0 += __uint_as_float(u.x << 16);
    x1 += __uint_as_float(u.x & 0xffff0000u);
    x2 += __uint_as_float(u.y << 16);
    x3 += __uint_as_float(u.y & 0xffff0000u);
}

__global__ __launch_bounds__(256) void agg_gather_kernel(
    const uint2* __restrict__ Hu, const int* __restrict__ rowptr,
    const int* __restrict__ cnt, const int* __restrict__ ssrc,
    const float* __restrict__ dinv, const float* __restrict__ bias,
    float* __restrict__ Out, int N)
{
    int node = blockIdx.x * 4 + (threadIdx.x >> 6);
    if (node >= N) return;
    int lane = threadIdx.x & 63;
    int half = lane >> 5;
    int l32  = lane & 31;
    size_t rsel = (size_t)node * 32 + l32;

    float a0 = 0.f, a1 = 0.f, a2 = 0.f, a3 = 0.f;
    float b0 = 0.f, b1 = 0.f, b2 = 0.f, b3 = 0.f;
    float c0 = 0.f, c1 = 0.f, c2 = 0.f, c3 = 0.f;
    float d0 = 0.f, d1 = 0.f, d2 = 0.f, d3 = 0.f;

    if (half == 0) acc2(Hu[rsel], a0, a1, a2, a3);   // self term

    int start = rowptr[node];
    int num   = cnt[node];
    int j = 0;
    for (; j + 8 <= num; j += 8) {
        int e = start + j + half;
        int s0 = ssrc[e];
        int s1 = ssrc[e + 2];
        int s2 = ssrc[e + 4];
        int s3 = ssrc[e + 6];
        uint2 u0 = Hu[(size_t)s0 * 32 + l32];
        uint2 u1 = Hu[(size_t)s1 * 32 + l32];
        uint2 u2 = Hu[(size_t)s2 * 32 + l32];
        uint2 u3 = Hu[(size_t)s3 * 32 + l32];
        acc2(u0, a0, a1, a2, a3);
        acc2(u1, b0, b1, b2, b3);
        acc2(u2, c0, c1, c2, c3);
        acc2(u3, d0, d1, d2, d3);
    }
    for (; j + 2 <= num; j += 2) {
        int s = ssrc[start + j + half];
        acc2(Hu[(size_t)s * 32 + l32], a0, a1, a2, a3);
    }
    if (half == 0 && j < num) {
        int s = ssrc[start + j];
        acc2(Hu[(size_t)s * 32 + l32], b0, b1, b2, b3);
    }

    a0 += b0 + c0 + d0;
    a1 += b1 + c1 + d1;
    a2 += b2 + c2 + d2;
    a3 += b3 + c3 + d3;
    a0 += __shfl_xor(a0, 32, 64);
    a1 += __shfl_xor(a1, 32, 64);
    a2 += __shfl_xor(a2, 32, 64);
    a3 += __shfl_xor(a3, 32, 64);

    if (half == 0) {
        float di = dinv[node];
        float4 bb = ((const float4*)bias)[l32];
        float4 o;
        o.x = fmaf(a0, di, bb.x);
        o.y = fmaf(a1, di, bb.y);
        o.z = fmaf(a2, di, bb.z);
        o.w = fmaf(a3, di, bb.w);
        ((float4*)Out)[rsel] = o;
    }
}

// ---------------- BN stats: per-column sum / sumsq ----------------
__global__ __launch_bounds__(256) void bn_stats_kernel(
    const float* __restrict__ A, float* __restrict__ sum, float* __restrict__ sq, int N)
{
    int c    = threadIdx.x & 127;
    int half = threadIdx.x >> 7;
    int r0   = blockIdx.x * 512;
    float s = 0.f, s2 = 0.f;
    for (int j = half; j < 512; j += 2) {
        int r = r0 + j;
        if (r < N) {
            float v = A[(size_t)r * 128 + c];
            s += v;
            s2 += v * v;
        }
    }
    __shared__ float ls[256], ls2[256];
    ls[threadIdx.x] = s;
    ls2[threadIdx.x] = s2;
    __syncthreads();
    if (threadIdx.x < 128) {
        float ts = ls[threadIdx.x] + ls[threadIdx.x + 128];
        float t2 = ls2[threadIdx.x] + ls2[threadIdx.x + 128];
        __hip_atomic_fetch_add(&sum[c], ts, __ATOMIC_RELAXED, __HIP_MEMORY_SCOPE_AGENT);
        __hip_atomic_fetch_add(&sq[c],  t2, __ATOMIC_RELAXED, __HIP_MEMORY_SCOPE_AGENT);
    }
}

__global__ void bn_final_kernel(const float* __restrict__ sum, const float* __restrict__ sq,
                                float* __restrict__ mu, float* __restrict__ rstd,
                                const float* __restrict__ gamma, const float* __restrict__ beta,
                                float* __restrict__ scale, float* __restrict__ shift, int N) {
    int c = threadIdx.x;
    if (c < 128) {
        float m = sum[c] / (float)N;
        float v = sq[c] / (float)N - m * m;
        float rs = rsqrtf(v + BN_EPS);
        mu[c] = m;
        rstd[c] = rs;
        if (scale) {
            float sc = gamma[c] * rs;
            scale[c] = sc;
            shift[c] = fmaf(-m, sc, beta[c]);
        }
    }
}

// ---------------- final BN apply in-place on d_out ----------------
__global__ void bn_apply_kernel(float* __restrict__ A, const float* __restrict__ gamma,
                                const float* __restrict__ beta, const float* __restrict__ mu,
                                const float* __restrict__ rstd, int N) {
    int i = blockIdx.x * blockDim.x + threadIdx.x;   // float4 index
    if (i >= N * 32) return;
    int c4 = i & 31;
    float4 v  = ((float4*)A)[i];
    float4 g  = ((const float4*)gamma)[c4];
    float4 b  = ((const float4*)beta)[c4];
    float4 m  = ((const float4*)mu)[c4];
    float4 rs = ((const float4*)rstd)[c4];
    v.x = fmaf(g.x * (v.x - m.x), rs.x, b.x);
    v.y = fmaf(g.y * (v.y - m.y), rs.y, b.y);
    v.z = fmaf(g.z * (v.z - m.z), rs.z, b.z);
    v.w = fmaf(g.w * (v.w - m.w), rs.w, b.w);
    ((float4*)A)[i] = v;
}

extern "C" void kernel_launch(void* const* d_in, const int* in_sizes, int n_in,
                              void* d_out, int out_size, void* d_ws, size_t ws_size,
                              hipStream_t stream) {
    const float* e_prev = (const float*)d_in[0];
    const int*   edges  = (const int*)d_in[1];
    const float* proj_W = (const float*)d_in[2];
    const float* proj_b = (const float*)d_in[3];
    const float* W1     = (const float*)d_in[4];
    const float* b1     = (const float*)d_in[5];
    const float* gamma1 = (const float*)d_in[6];
    const float* beta1  = (const float*)d_in[7];
    const float* W2     = (const float*)d_in[8];
    const float* b2     = (const float*)d_in[9];
    const float* gamma2 = (const float*)d_in[10];
    const float* beta2  = (const float*)d_in[11];
    float* out = (float*)d_out;

    const int N = in_sizes[0] / 256;
    const int E = in_sizes[1] / 2;
    const int* src = edges;
    const int* dst = edges + E;
    const int NB = (N + 1023) / 1024;

    char* p = (char*)d_ws;
    const size_t NH = (size_t)N * 128;
    __hip_bfloat16* Hs = (__hip_bfloat16*)p;  p += NH * 2;
    int* cnt    = (int*)p;  p += (size_t)N * 4;
    int* rowptr = (int*)p;  p += (size_t)N * 4;
    int* cursor = (int*)p;  p += (size_t)N * 4;
    int* ssrc   = (int*)p;  p += (size_t)E * 4;
    int* blk    = (int*)p;  p += ((NB + 255) & ~255) * 4;
    float* dinv = (float*)p; p += (size_t)N * 4;
    float* Wc   = (float*)p; p += 256 * 128 * 4;
    float* bc   = (float*)p; p += 128 * 4;
    float* stats = (float*)p; p += 1536 * 4;
    __hip_bfloat16* Wf1 = (__hip_bfloat16*)p; p += 256 * 128 * 2;
    __hip_bfloat16* Wf2 = (__hip_bfloat16*)p; p += 128 * 128 * 2;
    float* sum1 = stats,       *sq1 = stats + 128, *mu1 = stats + 256, *rs1 = stats + 384;
    float* sum2 = stats + 512, *sq2 = stats + 640, *mu2 = stats + 768, *rs2 = stats + 896;
    float* scale1 = stats + 1024, *shift1 = stats + 1152;

    // ---- graph preprocessing: degree + CSR by dst ----
    zero_kernel<<<(N + 255) / 256, 256, 0, stream>>>(cnt, stats, N);
    hist_kernel<<<(E + 255) / 256, 256, 0, stream>>>(dst, cnt, E);
    dinv_kernel<<<(N + 255) / 256, 256, 0, stream>>>(cnt, dinv, N);
    scan_part<<<NB, 256, 0, stream>>>(cnt, rowptr, blk, N);
    scan_blk<<<1, 64, 0, stream>>>(blk, NB);
    scan_add<<<(N + 255) / 256, 256, 0, stream>>>(rowptr, blk, cursor, N);
    fill_part_kernel<<<512, 256, 0, stream>>>(src, dst, cursor, ssrc, E, 8.0f / (float)N);

    // ---- folded weights + fragment packs ----
    wc_kernel<<<256, 128, 0, stream>>>(proj_W, W1, Wc);
    bc_kernel<<<1, 128, 0, stream>>>(proj_b, W1, bc);
    packW_kernel<256><<<(256 * 128 + 255) / 256, 256, 0, stream>>>(Wc, Wf1);
    packW_kernel<128><<<(128 * 128 + 255) / 256, 256, 0, stream>>>(W2, Wf2);

    const int gemm_grid = (N + 127) / 128;

    // ---- layer 1 ----
    mfma_gemm<256, false><<<gemm_grid, 256, 0, stream>>>(
        e_prev, (const short*)Wf1, bc, dinv, nullptr, nullptr, Hs, N);
    agg_gather_kernel<<<(N + 3) / 4, 256, 0, stream>>>(
        (const uint2*)Hs, rowptr, cnt, ssrc, dinv, b1, out, N);
    bn_stats_kernel<<<(N + 511) / 512, 256, 0, stream>>>(out, sum1, sq1, N);
    bn_final_kernel<<<1, 128, 0, stream>>>(sum1, sq1, mu1, rs1, gamma1, beta1, scale1, shift1, N);

    // ---- layer 2 ----
    mfma_gemm<128, true><<<gemm_grid, 256, 0, stream>>>(
        out, (const short*)Wf2, nullptr, dinv, scale1, shift1, Hs, N);
    agg_gather_kernel<<<(N + 3) / 4, 256, 0, stream>>>(
        (const uint2*)Hs, rowptr, cnt, ssrc, dinv, b2, out, N);
    bn_stats_kernel<<<(N + 511) / 512, 256, 0, stream>>>(out, sum2, sq2, N);
    bn_final_kernel<<<1, 128, 0, stream>>>(sum2, sq2, mu2, rs2, nullptr, nullptr, nullptr, nullptr, N);
    bn_apply_kernel<<<(N * 32 + 255) / 256, 256, 0, stream>>>(out, gamma2, beta2, mu2, rs2, N);
}